// Round 4
// baseline (370077.271 us; speedup 1.0000x reference)
//
#include <hip/hip_runtime.h>

// ---------------------------------------------------------------------------
// VanillaCRF forward on MI355X — R4: XCD-local persistent chains.
// Each chain pinned to one XCD (XCC_ID claim); h-state via normal L2-coherent
// loads/stores; per-chain barrier = workgroup-scope RMW on an L2-local line.
// Whh slices LDS-resident (144KB). Layer-1 input term precomputed by a
// parallel GEMM into masked-compressed bf16 XW1.
// kp layout: elem(row r, col k) at base[((k>>3)*R + r)*8 + (k&7)].
// Frags (m89/m91): A[m=lane&15][k=quad*8+j], B[k=quad*8+j][n=lane&15],
// D[row=quad*4+reg][col=lane&15].
// ---------------------------------------------------------------------------

typedef short v8s __attribute__((ext_vector_type(8)));
typedef float v4f __attribute__((ext_vector_type(4)));
typedef unsigned short u16;
typedef unsigned long long u64;

#define MFMA(a, b, c) __builtin_amdgcn_mfma_f32_16x16x32_bf16((a), (b), (c), 0, 0, 0)

static constexpr size_t SLOT64  = (size_t)96 * 64 * 8;    // u16 per 64x768 kp slot
static constexpr size_t SLOT16  = (size_t)96 * 16 * 8;
static constexpr size_t SLOT128 = (size_t)96 * 128 * 8;
static constexpr size_t CHXW1   = (size_t)3072 * 5120;    // u16 per chain (compressed)

static constexpr size_t OFF_CTR  = 0;                     static constexpr size_t SZ_CTR  = 4096;
static constexpr size_t OFF_EM   = OFF_CTR + SZ_CTR;      static constexpr size_t SZ_EM   = 131072;
static constexpr size_t OFF_XW0  = OFF_EM + SZ_EM;        static constexpr size_t SZ_XW0  = 6291456;
static constexpr size_t OFF_XW1S = OFF_XW0 + SZ_XW0;      static constexpr size_t SZ_XW1S = 6291456;
static constexpr size_t OFF_SEQ  = OFF_XW1S + SZ_XW1S;    static constexpr size_t SZ_SEQ  = 196608;
static constexpr size_t OFF_LABS = OFF_SEQ + SZ_SEQ;      static constexpr size_t SZ_LABS = 512;
static constexpr size_t OFF_F0   = OFF_LABS + SZ_LABS;    static constexpr size_t SZ_F0   = (size_t)2*129*SLOT16*2;
static constexpr size_t OFF_H0F  = OFF_F0 + SZ_F0;        static constexpr size_t SZ_H0F  = (size_t)2*SLOT128*2;
static constexpr size_t OFF_B0   = OFF_H0F + SZ_H0F;      static constexpr size_t SZ_S64  = (size_t)2*129*SLOT64*2;
static constexpr size_t OFF_F1   = OFF_B0 + SZ_S64;
static constexpr size_t OFF_B1   = OFF_F1 + SZ_S64;
static constexpr size_t OFF_XW1  = OFF_B1 + SZ_S64;       static constexpr size_t SZ_XW1  = (size_t)4*CHXW1*2;
static constexpr size_t WS_NEED  = OFF_XW1 + SZ_XW1;      // ~212 MB

static constexpr unsigned LDSA_BYTES = 147456;            // Whh slice [96 oct][96 row][8]
static constexpr unsigned LDSB_BYTES = 159744;            // + 12288 B xw stage

static __device__ __forceinline__ u16 f2b(float f) {
  unsigned u = __float_as_uint(f);
  return (u16)((u + 0x7FFFu + ((u >> 16) & 1u)) >> 16);
}
static __device__ __forceinline__ float b2f(u16 u) {
  return __uint_as_float(((unsigned)u) << 16);
}
static __device__ __forceinline__ float sigf(float x) { return 1.0f / (1.0f + __expf(-x)); }
static __device__ __forceinline__ float tanhfast(float x) {
  return 1.0f - 2.0f / (__expf(2.0f * x) + 1.0f);
}
static __device__ __forceinline__ float lse2(float a, float b) {
  float mx = fmaxf(a, b);
  return mx + __logf(__expf(a - mx) + __expf(b - mx));
}
static __device__ __forceinline__ int get_xcd() {
  // s_getreg_b32 hwreg(HW_REG_XCC_ID=20, off 0, size 32) [measured: learn_hip m09]
  return (int)(__builtin_amdgcn_s_getreg(63508) & 7u);
}
// compressed XW1: per t, stored p-range [16*(t>>5), 64); offset in u16 within chain
static __device__ __forceinline__ size_t xw1_off(int t) {
  int q = t >> 5;
  int sumw = 32 * (64 * q - 8 * q * (q - 1)) + (t & 31) * (64 - 16 * q);
  return (size_t)3072 * (size_t)sumw;
}

// XCD-local barrier: arrive = RMW add; poll = RMW add(0) (never L1-served).
static __device__ __forceinline__ void gbarx(unsigned* ctr, unsigned target) {
  __syncthreads();   // drains vmcnt: this block's stores are in L2 before arrive
  if (threadIdx.x == 0) {
    __hip_atomic_fetch_add(ctr, 1u, __ATOMIC_RELAXED, __HIP_MEMORY_SCOPE_WORKGROUP);
    int spins = 0;
    while (__hip_atomic_fetch_add(ctr, 0u, __ATOMIC_RELAXED, __HIP_MEMORY_SCOPE_WORKGROUP) < target) {
      __builtin_amdgcn_s_sleep(4);
      if (++spins > (1 << 20)) {  // safety valve: never hang the bench
        __hip_atomic_fetch_add(ctr, 1u << 20, __ATOMIC_RELAXED, __HIP_MEMORY_SCOPE_WORKGROUP);
        break;
      }
    }
  }
  __syncthreads();
}

// ---------------------------------------------------------------------------
__global__ void init_zero(u16* f0a, u16* f0b, u16* b0a, u16* b0b,
                          u16* f1a, u16* f1b, u16* b1a, u16* b1b, unsigned* ctrs) {
  int idx = blockIdx.x * 256 + threadIdx.x;   // grid 192 -> 49152 == SLOT64
  if (idx < 1024) ctrs[idx] = 0;
  if (idx < (int)SLOT16) { f0a[idx] = 0; f0b[idx] = 0; }
  b0a[idx] = 0; b0b[idx] = 0;
  f1a[idx] = 0; f1b[idx] = 0;
  b1a[idx] = 0; b1b[idx] = 0;
}

__global__ void build_seq(const float* user, const float* sysr, const int* ulab,
                          const int* slab, u16* seqkp, int* labs) {
  int idx = blockIdx.x * 256 + threadIdx.x;   // grid 384
  int t = idx / 768;
  int hh = idx - t * 768;
  float v = (t & 1) ? sysr[(t >> 1) * 768 + hh] : user[(t >> 1) * 768 + hh];
  seqkp[((size_t)(hh >> 3) * 128 + t) * 8 + (hh & 7)] = f2b(v);
  if (idx < 128) labs[idx] = (idx & 1) ? slab[idx >> 1] : ulab[idx >> 1];
}

// small GEMM: out[md] = A(128xK=768) @ W[md](768->3072 rows) + b
// mode 0: A=seqkp (shared), W stride 768, out TRANSPOSED [md][t][j][gate] fp32
// mode 1: A=h0f+m*SLOT128, W stride 1536 (first 768 cols), out plain [md*128+t][g]
__global__ void __launch_bounds__(256) xws_gemm(const u16* Akp, unsigned long long astride,
                                                const float* Wm0, const float* Wm1, int wstride,
                                                const float* bm0, const float* bm1,
                                                float* out, int mode) {
  __shared__ u16 lds[48 * 64 * 8];
  int tid = threadIdx.x, lane = tid & 63, wave = tid >> 6;
  int md = blockIdx.y, m = md >> 1, dir = md & 1;
  const u16* A = Akp + (size_t)m * astride;
  const float* W = (m ? Wm1 : Wm0) + (size_t)dir * 3072 * wstride;
  const float* b = (m ? bm1 : bm0) + dir * 3072;
  int g0 = blockIdx.x * 64;
  int quad = lane >> 4, l15 = lane & 15;
  v4f acc[2][4];
#pragma unroll
  for (int a = 0; a < 2; ++a)
#pragma unroll
    for (int nt = 0; nt < 4; ++nt) acc[a][nt] = (v4f){0.f, 0.f, 0.f, 0.f};

  for (int hfl = 0; hfl < 2; ++hfl) {
    if (hfl) __syncthreads();
    for (int it = 0; it < 12; ++it) {
      int ck = it * 256 + tid;
      int kb = ck >> 6, r = ck & 63;
      const float* s = W + (size_t)(g0 + r) * wstride + (size_t)(hfl * 48 + kb) * 8;
      union { u16 h[8]; int4 v; } u;
#pragma unroll
      for (int j = 0; j < 8; ++j) u.h[j] = f2b(s[j]);
      *(int4*)(lds + (size_t)ck * 8) = u.v;
    }
    __syncthreads();
    for (int lt = 0; lt < 12; ++lt) {
      int kblk = (hfl * 12 + lt) * 4 + quad;
      v8s a0 = ((const v8s*)A)[(size_t)kblk * 128 + (wave * 2 + 0) * 16 + l15];
      v8s a1 = ((const v8s*)A)[(size_t)kblk * 128 + (wave * 2 + 1) * 16 + l15];
#pragma unroll
      for (int nt = 0; nt < 4; ++nt) {
        v8s bb = *(const v8s*)(lds + ((size_t)((lt * 4 + quad) * 64) + nt * 16 + l15) * 8);
        acc[0][nt] = MFMA(a0, bb, acc[0][nt]);
        acc[1][nt] = MFMA(a1, bb, acc[1][nt]);
      }
    }
  }
#pragma unroll
  for (int a = 0; a < 2; ++a)
#pragma unroll
    for (int nt = 0; nt < 4; ++nt) {
      int g = g0 + nt * 16 + l15;
      float bv = b[g];
      int gate = g / 768, j = g - gate * 768;
#pragma unroll
      for (int r = 0; r < 4; ++r) {
        int trow = (wave * 2 + a) * 16 + quad * 4 + r;
        float val = acc[a][nt][r] + bv;
        if (mode == 0)
          out[((size_t)(md * 128 + trow) * 768 + j) * 4 + gate] = val;
        else
          out[(size_t)(md * 128 + trow) * 3072 + g] = val;
      }
    }
}

// XW1[md] (bf16, compressed p) = B0[m] @ Wih1[md][:,768:]^T + xw1s[md]
__global__ void __launch_bounds__(256) xw1big_k(const float* postWih1, const float* priWih1,
                                                const u16* B0, const float* xw1s, u16* XW1) {
  __shared__ u16 wlds[96 * 64 * 8];   // 96 KB
  int tid = threadIdx.x, lane = tid & 63, wave = tid >> 6;
  int quad = lane >> 4, l15 = lane & 15;
  int nb = blockIdx.x;                 // 0..47 gate-col block
  int gy = blockIdx.y;                 // pt*16 + tr
  int md = blockIdx.z;
  int pt = gy >> 4, tr = gy & 15;
  if (tr >= 4 * pt + 4) return;        // whole block inactive
  int m = md >> 1, dir = md & 1;
  int t0 = tr * 8;

  const float* Wf = (m ? priWih1 : postWih1) + (size_t)dir * 3072 * 1536;
  for (int it = 0; it < 24; ++it) {
    int idx = it * 256 + tid;          // 6144 v8s
    int oct = idx >> 6, r = idx & 63;
    const float* sp = Wf + (size_t)(nb * 64 + r) * 1536 + 768 + oct * 8;
    union { u16 h[8]; int4 v; } u;
#pragma unroll
    for (int q = 0; q < 8; ++q) u.h[q] = f2b(sp[q]);
    *(int4*)(wlds + (size_t)idx * 8) = u.v;
  }
  __syncthreads();

  int tA = t0 + wave * 2, tB = tA + 1;
  const v8s* A0 = (const v8s*)(B0 + (size_t)(m * 129 + tA) * SLOT64);
  const v8s* A1 = (const v8s*)(B0 + (size_t)(m * 129 + tB) * SLOT64);
  v4f acc[2][4];
#pragma unroll
  for (int a = 0; a < 2; ++a)
#pragma unroll
    for (int nt = 0; nt < 4; ++nt) acc[a][nt] = (v4f){0.f, 0.f, 0.f, 0.f};

#pragma unroll 4
  for (int kc = 0; kc < 24; ++kc) {
    int ko = kc * 4 + quad;
    v8s a0 = A0[(size_t)ko * 64 + pt * 16 + l15];
    v8s a1 = A1[(size_t)ko * 64 + pt * 16 + l15];
#pragma unroll
    for (int nt = 0; nt < 4; ++nt) {
      v8s bb = *(const v8s*)(wlds + ((size_t)(ko * 64 + nt * 16 + l15)) * 8);
      acc[0][nt] = MFMA(a0, bb, acc[0][nt]);
      acc[1][nt] = MFMA(a1, bb, acc[1][nt]);
    }
  }

  u16* chbase = XW1 + (size_t)md * CHXW1;
#pragma unroll
  for (int a = 0; a < 2; ++a) {
    int t = t0 + wave * 2 + a;
    if (t >= 32 * pt + 32) continue;   // this t inactive for this p-tile
    int q = t >> 5;
    int Wt = 64 - 16 * q, p0 = 16 * q;
    u16* base = chbase + xw1_off(t);
#pragma unroll
    for (int nt = 0; nt < 4; ++nt) {
      int g = nb * 64 + nt * 16 + l15;
      int gate = g / 768, j = g - gate * 768;
      float xs = xw1s[(size_t)(md * 128 + t) * 3072 + g];
#pragma unroll
      for (int r = 0; r < 4; ++r) {
        int p = pt * 16 + quad * 4 + r;
        base[((size_t)j * Wt + (p - p0)) * 4 + gate] = f2b(acc[a][nt][r] + xs);
      }
    }
  }
}

// ---------------------------------------------------------------------------
// persistA: layer 0. xcd 0/1 = bwd post/prior (64-batch), 2/3 = fwd post/prior
// (batch-degenerate, always-active). 32 blocks/XCD, 24 j-cols each.
__global__ void __launch_bounds__(256, 1) persistA_k(
    const float* __restrict__ postWhh0, const float* __restrict__ priWhh0,
    const float* __restrict__ xw0, u16* F0, u16* h0f, u16* B0, unsigned* ctrs) {
  extern __shared__ u16 lds[];   // [oct 96][row 96][8]
  __shared__ int s_xcd, s_slot;
  int tid = threadIdx.x, lane = tid & 63, wave = tid >> 6;
  int quad = lane >> 4, l15 = lane & 15;
  int b = l15 & 3, aa = l15 >> 2;
  if (tid == 0) {
    int x = get_xcd();
    s_xcd = x;
    s_slot = (int)__hip_atomic_fetch_add(&ctrs[x], 1u, __ATOMIC_RELAXED, __HIP_MEMORY_SCOPE_WORKGROUP);
  }
  __syncthreads();
  int xcd = s_xcd, slot = s_slot;
  if (xcd >= 4 || slot >= 32) return;
  int isf = xcd >> 1, m = xcd & 1;
  int dir = isf ? 0 : 1;
  int md = m * 2 + dir;
  int jb = slot * 24;

  // stage Whh0 slice (f2b on the fly): LDS[oct][r=4dj+gate] = W[gate*768+jb+dj][oct*8..]
  {
    const float* W = (m ? priWhh0 : postWhh0) + (size_t)dir * 3072 * 768;
    for (int it = 0; it < 36; ++it) {
      int idx = it * 256 + tid;         // 9216
      int oct = idx / 96, r = idx - oct * 96;
      const float* sp = W + (size_t)((r & 3) * 768 + jb + (r >> 2)) * 768 + oct * 8;
      union { u16 h[8]; int4 v; } u;
#pragma unroll
      for (int q = 0; q < 8; ++q) u.h[q] = f2b(sp[q]);
      *(int4*)(lds + (size_t)idx * 8) = u.v;
    }
  }
  __syncthreads();

  float cst[6], hst[6];
#pragma unroll
  for (int n = 0; n < 6; ++n) { cst[n] = 0.f; hst[n] = 0.f; }
  int p = wave * 16 + quad * 4 + b;     // this lane's kept batch row
  unsigned* bar = ctrs + 32 + xcd * 16;
  const float* xwch = xw0 + (size_t)md * 128 * 768 * 4;

#pragma unroll 1
  for (int s = 0; s < 128; ++s) {
    int t = isf ? s : 127 - s;
    // xw0 preload (transposed layout: 4 gates contiguous per (t,j))
    float4 xwv[6];
    {
      const float4* xb = (const float4*)(xwch + ((size_t)t * 768 + jb) * 4);
#pragma unroll
      for (int n = 0; n < 6; ++n) xwv[n] = xb[4 * n + aa];
    }
    v4f acc[6];
#pragma unroll
    for (int n = 0; n < 6; ++n) acc[n] = (v4f){0.f, 0.f, 0.f, 0.f};

    if (!isf) {
      const v8s* A = (const v8s*)(B0 + (size_t)(m * 129 + t + 1) * SLOT64);
      int arow = wave * 16 + l15;
#pragma unroll 4
      for (int kc = 0; kc < 24; ++kc) {
        int ko = kc * 4 + quad;
        v8s af = A[(size_t)ko * 64 + arow];
#pragma unroll
        for (int n = 0; n < 6; ++n) {
          v8s wf = *(const v8s*)(lds + ((size_t)(ko * 96 + 16 * n + l15)) * 8);
          acc[n] = MFMA(af, wf, acc[n]);
        }
      }
    } else if (wave == 0) {
      const v8s* A = (const v8s*)(F0 + (size_t)(m * 129 + t) * SLOT16);
#pragma unroll 4
      for (int kc = 0; kc < 24; ++kc) {
        int ko = kc * 4 + quad;
        v8s af = A[(size_t)ko * 16 + l15];
#pragma unroll
        for (int n = 0; n < 6; ++n) {
          v8s wf = *(const v8s*)(lds + ((size_t)(ko * 96 + 16 * n + l15)) * 8);
          acc[n] = MFMA(af, wf, acc[n]);
        }
      }
    }

    // epilogue
    u16* dstb = B0 + (size_t)(m * 129 + t) * SLOT64;
    u16* f0n = F0 + (size_t)(m * 129 + t + 1) * SLOT16;
#pragma unroll
    for (int n = 0; n < 6; ++n) {
      float gi_ = 0.f, gf_ = 0.f, gg_ = 0.f, go_ = 0.f;
#pragma unroll
      for (int rr = 0; rr < 4; ++rr) {
        float own = acc[n][rr];
        float v1 = __shfl_xor(own, 1, 64);
        float v2 = __shfl_xor(own, 2, 64);
        float v3 = __shfl_xor(own, 3, 64);
        float vv0 = own, vv1 = v1, vv2 = v2, vv3 = v3;
        // value carrying gate g arrived via xor mask (rr^g); rr compile-time
        float iV = (rr == 0) ? vv0 : (rr == 1) ? vv1 : (rr == 2) ? vv2 : vv3;
        float fV = ((rr ^ 1) == 0) ? vv0 : ((rr ^ 1) == 1) ? vv1 : ((rr ^ 1) == 2) ? vv2 : vv3;
        float gV = ((rr ^ 2) == 0) ? vv0 : ((rr ^ 2) == 1) ? vv1 : ((rr ^ 2) == 2) ? vv2 : vv3;
        float oV = ((rr ^ 3) == 0) ? vv0 : ((rr ^ 3) == 1) ? vv1 : ((rr ^ 3) == 2) ? vv2 : vv3;
        if (b == rr) { gi_ = iV; gf_ = fV; gg_ = gV; go_ = oV; }
      }
      float gi = sigf(gi_ + xwv[n].x), gf = sigf(gf_ + xwv[n].y);
      float gg = tanhfast(gg_ + xwv[n].z), go = sigf(go_ + xwv[n].w);
      float cn = gf * cst[n] + gi * gg;
      float hn = go * tanhfast(cn);
      bool act = isf ? true : (t < 2 * p + 2 - m);
      cst[n] = act ? cn : cst[n];
      float he = act ? hn : hst[n];
      hst[n] = he;
      if (!isf) {
        int hv = (int)f2b(he);
        int w1 = __shfl_xor(hv, 4, 64);
        int w2 = __shfl_xor(hv, 8, 64);
        int w3 = __shfl_xor(hv, 12, 64);
        if (aa == 0) {
          u64 pk = (u64)(u16)hv | ((u64)(u16)w1 << 16) | ((u64)(u16)w2 << 32) | ((u64)(u16)w3 << 48);
          int j = jb + 4 * n;
          *(u64*)(dstb + (((size_t)(j >> 3) * 64 + p) * 8 + (j & 7))) = pk;
        }
      } else {
        if (wave == 0 && quad == 0 && b == 0) {   // p == 0 lanes, dj = 4n+aa
          int j = jb + 4 * n + aa;
          u16 hb16 = f2b(hn);
          f0n[((size_t)(j >> 3) * 16) * 8 + (j & 7)] = hb16;
          h0f[(size_t)m * SLOT128 + ((size_t)(j >> 3) * 128 + t) * 8 + (j & 7)] = hb16;
        }
      }
    }
    gbarx(bar, (unsigned)(s + 1) * 32);
  }
}

// ---------------------------------------------------------------------------
// persistB: layer 1. xcd = md (0: fwd1-post, 1: bwd1-post, 2: fwd1-pri, 3: bwd1-pri)
__global__ void __launch_bounds__(256, 1) persistB_k(
    const float* __restrict__ postWhh1, const float* __restrict__ priWhh1,
    const u16* __restrict__ XW1, u16* F1, u16* B1, unsigned* ctrs) {
  extern __shared__ u16 lds[];          // [0,73728) W; [73728, 79872) xw stage
  u16* xwstage = lds + 73728;
  __shared__ int s_xcd, s_slot;
  int tid = threadIdx.x, lane = tid & 63, wave = tid >> 6;
  int quad = lane >> 4, l15 = lane & 15;
  int b = l15 & 3, aa = l15 >> 2;
  if (tid == 0) {
    int x = get_xcd();
    s_xcd = x;
    s_slot = (int)__hip_atomic_fetch_add(&ctrs[8 + x], 1u, __ATOMIC_RELAXED, __HIP_MEMORY_SCOPE_WORKGROUP);
  }
  __syncthreads();
  int xcd = s_xcd, slot = s_slot;
  if (xcd >= 4 || slot >= 32) return;
  int md = xcd, m = md >> 1, dir = md & 1;
  int jb = slot * 24;

  {
    const float* W = (m ? priWhh1 : postWhh1) + (size_t)dir * 3072 * 768;
    for (int it = 0; it < 36; ++it) {
      int idx = it * 256 + tid;
      int oct = idx / 96, r = idx - oct * 96;
      const float* sp = W + (size_t)((r & 3) * 768 + jb + (r >> 2)) * 768 + oct * 8;
      union { u16 h[8]; int4 v; } u;
#pragma unroll
      for (int q = 0; q < 8; ++q) u.h[q] = f2b(sp[q]);
      *(int4*)(lds + (size_t)idx * 8) = u.v;
    }
  }
  __syncthreads();

  float cst[6], hst[6];
#pragma unroll
  for (int n = 0; n < 6; ++n) { cst[n] = 0.f; hst[n] = 0.f; }
  int p = wave * 16 + quad * 4 + b;
  unsigned* bar = ctrs + 32 + (4 + md) * 16;
  const u16* chxw = XW1 + (size_t)md * CHXW1;
  u16* Fsl = (dir ? B1 : F1) + (size_t)m * 129 * SLOT64;

#pragma unroll 1
  for (int s = 0; s < 128; ++s) {
    int t = dir ? 127 - s : s;
    // stage XW1 slice -> LDS [dj][64 p][4 gates] (u64 = one (dj,p) gate-quad)
    {
      int q = t >> 5;
      int Wt = 64 - 16 * q, p0 = 16 * q;
      const u16* src = chxw + xw1_off(t) + (size_t)jb * Wt * 4;
      int cnt = 24 * Wt;
      for (int idx = tid; idx < cnt; idx += 256) {
        int dj = idx / Wt, pp = idx - dj * Wt;
        u64 v = *(const u64*)(src + (size_t)(dj * Wt + pp) * 4);
        *(u64*)(xwstage + ((size_t)(dj * 64 + p0 + pp)) * 4) = v;
      }
    }
    // recurrent MFMA
    const v8s* A = (const v8s*)(Fsl + (size_t)(dir ? t + 1 : t) * SLOT64);
    v4f acc[6];
#pragma unroll
    for (int n = 0; n < 6; ++n) acc[n] = (v4f){0.f, 0.f, 0.f, 0.f};
    int arow = wave * 16 + l15;
#pragma unroll 4
    for (int kc = 0; kc < 24; ++kc) {
      int ko = kc * 4 + quad;
      v8s af = A[(size_t)ko * 64 + arow];
#pragma unroll
      for (int n = 0; n < 6; ++n) {
        v8s wf = *(const v8s*)(lds + ((size_t)(ko * 96 + 16 * n + l15)) * 8);
        acc[n] = MFMA(af, wf, acc[n]);
      }
    }
    __syncthreads();   // xw stage visible to all

    u16* dstb = Fsl + (size_t)(dir ? t : t + 1) * SLOT64;
#pragma unroll
    for (int n = 0; n < 6; ++n) {
      float gi_ = 0.f, gf_ = 0.f, gg_ = 0.f, go_ = 0.f;
#pragma unroll
      for (int rr = 0; rr < 4; ++rr) {
        float own = acc[n][rr];
        float v1 = __shfl_xor(own, 1, 64);
        float v2 = __shfl_xor(own, 2, 64);
        float v3 = __shfl_xor(own, 3, 64);
        float iV = (rr == 0) ? own : (rr == 1) ? v1 : (rr == 2) ? v2 : v3;
        float fV = ((rr ^ 1) == 0) ? own : ((rr ^ 1) == 1) ? v1 : ((rr ^ 1) == 2) ? v2 : v3;
        float gV = ((rr ^ 2) == 0) ? own : ((rr ^ 2) == 1) ? v1 : ((rr ^ 2) == 2) ? v2 : v3;
        float oV = ((rr ^ 3) == 0) ? own : ((rr ^ 3) == 1) ? v1 : ((rr ^ 3) == 2) ? v2 : v3;
        if (b == rr) { gi_ = iV; gf_ = fV; gg_ = gV; go_ = oV; }
      }
      u64 xq = *(const u64*)(xwstage + ((size_t)((4 * n + aa) * 64 + p)) * 4);
      float xi = b2f((u16)xq), xf = b2f((u16)(xq >> 16));
      float xg = b2f((u16)(xq >> 32)), xo = b2f((u16)(xq >> 48));
      float gi = sigf(gi_ + xi), gf = sigf(gf_ + xf);
      float gg = tanhfast(gg_ + xg), go = sigf(go_ + xo);
      float cn = gf * cst[n] + gi * gg;
      float hn = go * tanhfast(cn);
      bool act = (t < 2 * p + 2 - m);
      cst[n] = act ? cn : cst[n];
      float he = act ? hn : hst[n];
      hst[n] = he;
      int hv = (int)f2b(he);
      int w1 = __shfl_xor(hv, 4, 64);
      int w2 = __shfl_xor(hv, 8, 64);
      int w3 = __shfl_xor(hv, 12, 64);
      if (aa == 0) {
        u64 pk = (u64)(u16)hv | ((u64)(u16)w1 << 16) | ((u64)(u16)w2 << 32) | ((u64)(u16)w3 << 48);
        int j = jb + 4 * n;
        *(u64*)(dstb + (((size_t)(j >> 3) * 64 + p) * 8 + (j & 7))) = pk;
      }
    }
    gbarx(bar, (unsigned)(s + 1) * 32);
  }
}

__global__ void __launch_bounds__(256) em_k(const u16* F1, const u16* B1,
                                            const float* pW0, const float* pb0,
                                            const float* pW1, const float* pb1, float* em) {
  int wid = blockIdx.x * 4 + (threadIdx.x >> 6);
  int lane = threadIdx.x & 63;
  int m = wid >> 13;
  int rem = wid & 8191;
  int p = rem >> 7;
  int t = rem & 127;
  const u16* hf = F1 + (size_t)(m * 129 + t + 1) * SLOT64;
  const u16* hb = B1 + (size_t)(m * 129 + t) * SLOT64;
  const float* Pw = m ? pW1 : pW0;
  const float* Pb = m ? pb1 : pb0;
  float s0 = 0.f, s1 = 0.f;
#pragma unroll
  for (int i = 0; i < 12; ++i) {
    int j = i * 64 + lane;
    size_t o = ((size_t)(j >> 3) * 64 + p) * 8 + (j & 7);
    float vf = b2f(hf[o]);
    float vb = b2f(hb[o]);
    s0 += Pw[j] * vf + Pw[768 + j] * vb;
    s1 += Pw[1536 + j] * vf + Pw[2304 + j] * vb;
  }
  for (int off = 32; off; off >>= 1) {
    s0 += __shfl_down(s0, off, 64);
    s1 += __shfl_down(s1, off, 64);
  }
  if (lane == 0) {
    em[((size_t)(m * 64 + p) * 128 + t) * 2 + 0] = s0 + Pb[0];
    em[((size_t)(m * 64 + p) * 128 + t) * 2 + 1] = s1 + Pb[1];
  }
}

__global__ void final_k(const float* em, const int* labs, const float* T, float* out) {
  int p = threadIdx.x;
  const float* emP = em + (size_t)p * 128 * 2;
  int lp = 2 * p + 2;
  float T00 = T[0], T01 = T[1], T10 = T[2], T11 = T[3];
  int prevlab = labs[0];
  float gold = emP[prevlab];
  for (int t = 1; t < lp; ++t) {
    int lb = labs[t];
    gold += emP[t * 2 + lb] + (prevlab ? (lb ? T11 : T10) : (lb ? T01 : T00));
    prevlab = lb;
  }
  float a0 = emP[0], a1 = emP[1];
  for (int t = 1; t < lp; ++t) {
    float n0 = lse2(a0 + T00, a1 + T10) + emP[t * 2];
    float n1 = lse2(a0 + T01, a1 + T11) + emP[t * 2 + 1];
    a0 = n0; a1 = n1;
  }
  float crf = lse2(a0, a1) - gold;
  const float* emR = em + (size_t)(64 + p) * 128 * 2;
  int lpr = 2 * p + 1;
  float d0 = emR[(lpr - 1) * 2 + 0] - emP[(lp - 1) * 2 + 0];
  float d1 = emR[(lpr - 1) * 2 + 1] - emP[(lp - 1) * 2 + 1];
  float mse = d0 * d0 + d1 * d1;
  for (int off = 32; off; off >>= 1) {
    crf += __shfl_down(crf, off, 64);
    mse += __shfl_down(mse, off, 64);
  }
  if (p == 0) {
    float lc = crf / 64.f;
    float lm = mse / 128.f;
    out[0] = lc;
    out[1] = lm;
    out[2] = lc + 0.1f * lm;
  }
}

// ---------------------------------------------------------------------------
extern "C" void kernel_launch(void* const* d_in, const int* in_sizes, int n_in,
                              void* d_out, int out_size, void* d_ws, size_t ws_size,
                              hipStream_t stream) {
  (void)in_sizes; (void)n_in; (void)out_size;
  if (ws_size < WS_NEED) return;   // diagnosable: output stays poisoned

  const float* user     = (const float*)d_in[0];
  const float* sysr     = (const float*)d_in[1];
  const float* postWih0 = (const float*)d_in[2];
  const float* postWhh0 = (const float*)d_in[3];
  const float* postb0   = (const float*)d_in[4];
  const float* postWih1 = (const float*)d_in[5];
  const float* postWhh1 = (const float*)d_in[6];
  const float* postb1   = (const float*)d_in[7];
  const float* priWih0  = (const float*)d_in[8];
  const float* priWhh0  = (const float*)d_in[9];
  const float* prib0    = (const float*)d_in[10];
  const float* priWih1  = (const float*)d_in[11];
  const float* priWhh1  = (const float*)d_in[12];
  const float* prib1    = (const float*)d_in[13];
  const float* postPW   = (const float*)d_in[14];
  const float* postPb   = (const float*)d_in[15];
  const float* priPW    = (const float*)d_in[16];
  const float* priPb    = (const float*)d_in[17];
  const float* trans    = (const float*)d_in[18];
  const int*   ulab     = (const int*)d_in[19];
  const int*   slab     = (const int*)d_in[20];
  float* out = (float*)d_out;

  char* w = (char*)d_ws;
  unsigned* ctrs = (unsigned*)(w + OFF_CTR);
  float* em    = (float*)(w + OFF_EM);
  float* xw0   = (float*)(w + OFF_XW0);
  float* xw1s  = (float*)(w + OFF_XW1S);
  u16* seqkp   = (u16*)(w + OFF_SEQ);
  int* labs    = (int*)(w + OFF_LABS);
  u16* F0      = (u16*)(w + OFF_F0);
  u16* h0f     = (u16*)(w + OFF_H0F);
  u16* B0      = (u16*)(w + OFF_B0);
  u16* F1      = (u16*)(w + OFF_F1);
  u16* B1      = (u16*)(w + OFF_B1);
  u16* XW1     = (u16*)(w + OFF_XW1);

  init_zero<<<192, 256, 0, stream>>>(
      F0, F0 + (size_t)129 * SLOT16,
      B0 + (size_t)128 * SLOT64, B0 + (size_t)(129 + 128) * SLOT64,
      F1, F1 + (size_t)129 * SLOT64,
      B1 + (size_t)128 * SLOT64, B1 + (size_t)(129 + 128) * SLOT64, ctrs);

  build_seq<<<384, 256, 0, stream>>>(user, sysr, ulab, slab, seqkp, labs);

  xws_gemm<<<dim3(48, 4), 256, 0, stream>>>(seqkp, 0ULL, postWih0, priWih0, 768,
                                            postb0, prib0, xw0, 0);

  {
    void* args[] = {(void*)&postWhh0, (void*)&priWhh0, (void*)&xw0,
                    (void*)&F0, (void*)&h0f, (void*)&B0, (void*)&ctrs};
    hipError_t e = hipLaunchCooperativeKernel((const void*)persistA_k, dim3(256), dim3(256),
                                              args, LDSA_BYTES, stream);
    if (e != hipSuccess)
      persistA_k<<<256, 256, LDSA_BYTES, stream>>>(postWhh0, priWhh0, xw0, F0, h0f, B0, ctrs);
  }

  xws_gemm<<<dim3(48, 4), 256, 0, stream>>>(h0f, (unsigned long long)SLOT128,
                                            postWih1, priWih1, 1536, postb1, prib1, xw1s, 1);

  xw1big_k<<<dim3(48, 64, 4), 256, 0, stream>>>(postWih1, priWih1, B0, xw1s, XW1);

  {
    void* args[] = {(void*)&postWhh1, (void*)&priWhh1, (void*)&XW1,
                    (void*)&F1, (void*)&B1, (void*)&ctrs};
    hipError_t e = hipLaunchCooperativeKernel((const void*)persistB_k, dim3(256), dim3(256),
                                              args, LDSB_BYTES, stream);
    if (e != hipSuccess)
      persistB_k<<<256, 256, LDSB_BYTES, stream>>>(postWhh1, priWhh1, XW1, F1, B1, ctrs);
  }

  em_k<<<4096, 256, 0, stream>>>(F1, B1, postPW, postPb, priPW, priPb, em);

  final_k<<<1, 64, 0, stream>>>(em, labs, trans, out);
}